// Round 7
// baseline (104.691 us; speedup 1.0000x reference)
//
#include <hip/hip_runtime.h>

#define Bn 2
#define Nn 4096
#define Cn 256
#define Kn 64
#define CH 64                 // points per chunk
#define NCH (Nn / CH)         // 64 chunks
#define NBG 2                 // box groups
#define GB 32                 // boxes per group

// ---------------- Kernel A: streaming scatter-pool ----------------
// grid (NCH, Bn, NBG), 256 threads (one per channel).
// Streams 64 contiguous feature rows (addresses static -> pipelined),
// pushes each row into the <=32 boxes containing the point via LDS fmax.
__global__ __launch_bounds__(256) void pool_stream(
    const float* __restrict__ points,      // (B,N,3)
    const float* __restrict__ feats,       // (B,N,C)
    const float* __restrict__ proposals,   // (B,K,7)
    float* __restrict__ partial)           // (B,NBG,GB,NCH,256)
{
    const int chunk = blockIdx.x;
    const int b     = blockIdx.y;
    const int g     = blockIdx.z;
    const int tid   = threadIdx.x;         // channel

    __shared__ unsigned s_mask[CH];
    __shared__ float    s_pool[GB][Cn];    // 32 KiB

    #pragma unroll
    for (int box = 0; box < GB; ++box) s_pool[box][tid] = -INFINITY;
    if (tid < CH) s_mask[tid] = 0u;
    __syncthreads();

    // --- point->box masks: thread t tests point (t&63) vs 8 boxes ---
    {
        const int p  = tid & (CH - 1);
        const int b0 = (tid >> 6) * 8;     // 0,8,16,24 within group
        const int n  = chunk * CH + p;
        const float px = points[((size_t)b * Nn + n) * 3 + 0];
        const float py = points[((size_t)b * Nn + n) * 3 + 1];
        const float pz = points[((size_t)b * Nn + n) * 3 + 2];
        unsigned m = 0u;
        #pragma unroll
        for (int j = 0; j < 8; ++j) {
            const int k = g * GB + b0 + j;
            const float* prop = proposals + ((size_t)b * Kn + k) * 7;
            const float cx = prop[0], cy = prop[1], cz = prop[2];
            const float hx = prop[3] * 0.5f, hy = prop[4] * 0.5f, hz = prop[5] * 0.5f;
            const bool in = (px > cx - hx) & (px < cx + hx) &
                            (py > cy - hy) & (py < cy + hy) &
                            (pz > cz - hz) & (pz < cz + hz);
            if (in) m |= (1u << (b0 + j));
        }
        if (m) atomicOr(&s_mask[p], m);
    }
    __syncthreads();

    // --- stream 64 rows, unconditional, 4 independent loads per iter ---
    const float* fb = feats + ((size_t)b * Nn + (size_t)chunk * CH) * Cn + tid;
    for (int p = 0; p < CH; p += 4) {
        const float f0 = fb[(p + 0) * Cn];
        const float f1 = fb[(p + 1) * Cn];
        const float f2 = fb[(p + 2) * Cn];
        const float f3 = fb[(p + 3) * Cn];
        // masks are wave-uniform -> scalar loops, no divergence
        unsigned m0 = __builtin_amdgcn_readfirstlane(s_mask[p + 0]);
        unsigned m1 = __builtin_amdgcn_readfirstlane(s_mask[p + 1]);
        unsigned m2 = __builtin_amdgcn_readfirstlane(s_mask[p + 2]);
        unsigned m3 = __builtin_amdgcn_readfirstlane(s_mask[p + 3]);
        while (m0) { const int bx = __ffs(m0) - 1; m0 &= m0 - 1;
                     s_pool[bx][tid] = fmaxf(s_pool[bx][tid], f0); }
        while (m1) { const int bx = __ffs(m1) - 1; m1 &= m1 - 1;
                     s_pool[bx][tid] = fmaxf(s_pool[bx][tid], f1); }
        while (m2) { const int bx = __ffs(m2) - 1; m2 &= m2 - 1;
                     s_pool[bx][tid] = fmaxf(s_pool[bx][tid], f2); }
        while (m3) { const int bx = __ffs(m3) - 1; m3 &= m3 - 1;
                     s_pool[bx][tid] = fmaxf(s_pool[bx][tid], f3); }
    }
    __syncthreads();

    // --- write 32 partial rows (coalesced 1 KiB stores) ---
    float* dst = partial + (((size_t)(b * NBG + g) * GB) * NCH + chunk) * Cn + tid;
    #pragma unroll
    for (int box = 0; box < GB; ++box)
        dst[(size_t)box * NCH * Cn] = s_pool[box][tid];
}

// ---------------- Kernel B: chunk-reduce + MLP ----------------
// 128 blocks (one per box), 256 threads.
__global__ __launch_bounds__(256) void reduce_mlp(
    const float* __restrict__ partial,     // (B,NBG,GB,NCH,256)
    const float* __restrict__ W1,          // (C,256)
    const float* __restrict__ b1,
    const float* __restrict__ W2,          // (256,256)
    const float* __restrict__ b2,
    float* __restrict__ out)               // (B,K,256)
{
    const int bk  = blockIdx.x;
    const int b   = bk / Kn;
    const int k   = bk % Kn;
    const int g   = k / GB;
    const int box = k % GB;
    const int tid = threadIdx.x;

    __shared__ float s_vec[Cn];

    const float* src = partial +
        (((size_t)(b * NBG + g) * GB + box) * NCH) * Cn + tid;
    float m = -INFINITY;
    #pragma unroll 8
    for (int ch = 0; ch < NCH; ++ch)
        m = fmaxf(m, src[(size_t)ch * Cn]);
    if (m == -INFINITY) m = 0.0f;          // empty box -> 0 (matches reference)
    s_vec[tid] = m;
    __syncthreads();

    float acc = b1[tid];
    #pragma unroll 16
    for (int c = 0; c < Cn; ++c)
        acc = fmaf(s_vec[c], W1[c * 256 + tid], acc);
    const float h = fmaxf(acc, 0.0f);
    __syncthreads();
    s_vec[tid] = h;
    __syncthreads();

    float acc2 = b2[tid];
    #pragma unroll 16
    for (int c = 0; c < 256; ++c)
        acc2 = fmaf(s_vec[c], W2[c * 256 + tid], acc2);
    out[(size_t)bk * 256 + tid] = fmaxf(acc2, 0.0f);
}

extern "C" void kernel_launch(void* const* d_in, const int* in_sizes, int n_in,
                              void* d_out, int out_size, void* d_ws, size_t ws_size,
                              hipStream_t stream) {
    const float* points    = (const float*)d_in[0];
    const float* feats     = (const float*)d_in[1];
    const float* proposals = (const float*)d_in[2];
    const float* W1        = (const float*)d_in[3];
    const float* b1        = (const float*)d_in[4];
    const float* W2        = (const float*)d_in[5];
    const float* b2        = (const float*)d_in[6];
    float* out             = (float*)d_out;
    float* partial         = (float*)d_ws;  // (B,NBG,GB,NCH,256) = 8 MiB

    dim3 gridA(NCH, Bn, NBG);
    pool_stream<<<gridA, 256, 0, stream>>>(points, feats, proposals, partial);
    reduce_mlp<<<Bn * Kn, 256, 0, stream>>>(partial, W1, b1, W2, b2, out);
}